// Round 1
// baseline (434.698 us; speedup 1.0000x reference)
//
#include <hip/hip_runtime.h>
#include <hip/hip_bf16.h>

#define BM 128
#define BN 128
#define BK 32

typedef __attribute__((ext_vector_type(8))) short short8;   // 8 bf16 = 4 VGPRs
typedef __attribute__((ext_vector_type(4))) float floatx4;  // MFMA 16x16 C/D

// ---------- bf16 split helpers (RN-even, inputs are finite normals) ----------
__device__ inline unsigned short f2bf(float f) {
    unsigned u = __float_as_uint(f);
    unsigned r = (u + 0x7fffu + ((u >> 16) & 1u)) >> 16;
    return (unsigned short)r;
}
__device__ inline float bf2f(unsigned short s) {
    return __uint_as_float(((unsigned)s) << 16);
}

// ---------- prepass: fp32 -> (hi, lo) bf16 arrays ----------
__global__ __launch_bounds__(256) void split_fp32_bf16(
        const float* __restrict__ src,
        unsigned short* __restrict__ hi, unsigned short* __restrict__ lo, int n4) {
    int i = blockIdx.x * blockDim.x + threadIdx.x;
    int stride = gridDim.x * blockDim.x;
    const float4* s4 = (const float4*)src;
    ushort4* h4 = (ushort4*)hi;
    ushort4* l4 = (ushort4*)lo;
    for (; i < n4; i += stride) {
        float4 v = s4[i];
        ushort4 hv, lv;
        hv.x = f2bf(v.x); lv.x = f2bf(v.x - bf2f(hv.x));
        hv.y = f2bf(v.y); lv.y = f2bf(v.y - bf2f(hv.y));
        hv.z = f2bf(v.z); lv.z = f2bf(v.z - bf2f(hv.z));
        hv.w = f2bf(v.w); lv.w = f2bf(v.w - bf2f(hv.w));
        h4[i] = hv;
        l4[i] = lv;
    }
}

// ---------- fused bf16x3 GEMM + gumbel-sigmoid epilogue ----------
// C[m][n] = sum_k x[m][k]*W[n][k]  (gemm_bt: both operands row-major along K)
// out = sigmoid((C + b + g1 - g2) / 0.1)

#define AS1U(p) ((const __attribute__((address_space(1))) unsigned int*)(p))
#define AS3U(p) ((__attribute__((address_space(3))) unsigned int*)(p))

__device__ inline int swz(int row) {  // chunk swizzle: 2-way (free) LDS aliasing
    return (row & 3) ^ ((row >> 2) & 1);
}

__global__ __launch_bounds__(256) void gumbel_gemm(
        const unsigned short* __restrict__ xh, const unsigned short* __restrict__ xl,
        const unsigned short* __restrict__ wh, const unsigned short* __restrict__ wl,
        const float* __restrict__ bias, const float* __restrict__ u1,
        const float* __restrict__ u2, float* __restrict__ out,
        int M, int N, int K) {
    __shared__ short As_h[BM * BK];
    __shared__ short As_l[BM * BK];
    __shared__ short Bs_h[BN * BK];
    __shared__ short Bs_l[BN * BK];

    const int tid  = threadIdx.x;
    const int lane = tid & 63;
    const int wave = tid >> 6;

    // XCD-affinity remap: all 8 bx of a row-panel share (bid % 8) -> same XCD
    const int bid = blockIdx.x;          // 1D grid of (M/BM)*(N/BN) blocks
    const int nbx = N / BN;
    const int by  = bid & (M / BM - 1);  // M/BM is power of two (128)
    const int bx  = bid / (M / BM);
    (void)nbx;
    const int bm = by * BM;
    const int bn = bx * BN;

    // --- staging setup: 512 16B chunks per array; wave w owns slots [w*128, w*128+128) ---
    int slot0 = wave * 128 + lane;
    int slot1 = slot0 + 64;
    int arow0 = slot0 >> 2, arow1 = slot1 >> 2;
    int gcc0 = (slot0 & 3) ^ swz(arow0);
    int gcc1 = (slot1 & 3) ^ swz(arow1);
    // element offsets (shorts) into x/w arrays, sans kb
    int aoff0 = (bm + arow0) * K + gcc0 * 8;
    int aoff1 = (bm + arow1) * K + gcc1 * 8;
    int boff0 = (bn + arow0) * K + gcc0 * 8;
    int boff1 = (bn + arow1) * K + gcc1 * 8;
    int ls0 = slot0 * 8;  // LDS short offset of this lane's 16B slot
    int ls1 = slot1 * 8;

    // --- fragment addressing ---
    const int r16  = lane & 15;
    const int quad = lane >> 4;
    const int wm = (wave & 1) * 64;
    const int wn = (wave >> 1) * 64;

    floatx4 acc[4][4] = {};

    int aro[4], bro[4];
#pragma unroll
    for (int i = 0; i < 4; i++) {
        int rowa = wm + i * 16 + r16;
        aro[i] = rowa * BK + (quad ^ swz(rowa)) * 8;
        int rowb = wn + i * 16 + r16;
        bro[i] = rowb * BK + (quad ^ swz(rowb)) * 8;
    }

    for (int kb = 0; kb < K; kb += BK) {
        // stage 4 tiles (32 KB) via direct-to-LDS 16B DMA
        __builtin_amdgcn_global_load_lds(AS1U(xh + aoff0 + kb), AS3U(As_h + ls0), 16, 0, 0);
        __builtin_amdgcn_global_load_lds(AS1U(xh + aoff1 + kb), AS3U(As_h + ls1), 16, 0, 0);
        __builtin_amdgcn_global_load_lds(AS1U(xl + aoff0 + kb), AS3U(As_l + ls0), 16, 0, 0);
        __builtin_amdgcn_global_load_lds(AS1U(xl + aoff1 + kb), AS3U(As_l + ls1), 16, 0, 0);
        __builtin_amdgcn_global_load_lds(AS1U(wh + boff0 + kb), AS3U(Bs_h + ls0), 16, 0, 0);
        __builtin_amdgcn_global_load_lds(AS1U(wh + boff1 + kb), AS3U(Bs_h + ls1), 16, 0, 0);
        __builtin_amdgcn_global_load_lds(AS1U(wl + boff0 + kb), AS3U(Bs_l + ls0), 16, 0, 0);
        __builtin_amdgcn_global_load_lds(AS1U(wl + boff1 + kb), AS3U(Bs_l + ls1), 16, 0, 0);
        __syncthreads();

        short8 ah[4], al[4], bh[4], bl[4];
#pragma unroll
        for (int i = 0; i < 4; i++) {
            ah[i] = *(const short8*)(As_h + aro[i]);
            al[i] = *(const short8*)(As_l + aro[i]);
            bh[i] = *(const short8*)(Bs_h + bro[i]);
            bl[i] = *(const short8*)(Bs_l + bro[i]);
        }
#pragma unroll
        for (int i = 0; i < 4; i++) {
#pragma unroll
            for (int j = 0; j < 4; j++) {
                acc[i][j] = __builtin_amdgcn_mfma_f32_16x16x32_bf16(ah[i], bh[j], acc[i][j], 0, 0, 0);
                acc[i][j] = __builtin_amdgcn_mfma_f32_16x16x32_bf16(ah[i], bl[j], acc[i][j], 0, 0, 0);
                acc[i][j] = __builtin_amdgcn_mfma_f32_16x16x32_bf16(al[i], bh[j], acc[i][j], 0, 0, 0);
            }
        }
        __syncthreads();
    }

    // --- epilogue: C/D layout col=lane&15, row=quad*4+reg ---
    const float inv_t = 10.0f;  // 1/TEMP
#pragma unroll
    for (int j = 0; j < 4; j++) {
        int gn = bn + wn + j * 16 + r16;
        float bv = bias[gn];
#pragma unroll
        for (int i = 0; i < 4; i++) {
            int gm0 = bm + wm + i * 16 + quad * 4;
#pragma unroll
            for (int r = 0; r < 4; r++) {
                int idx = (gm0 + r) * N + gn;
                float l = acc[i][j][r] + bv;
                float a1 = -__logf(u1[idx]);   // -log(u1) > 0
                float a2 = -__logf(u2[idx]);
                // g1 - g2 = -log(a1) + log(a2) = log(a2/a1)
                float z = (l + __logf(a2 / a1)) * inv_t;
                out[idx] = 1.0f / (1.0f + __expf(-z));
            }
        }
    }
}

extern "C" void kernel_launch(void* const* d_in, const int* in_sizes, int n_in,
                              void* d_out, int out_size, void* d_ws, size_t ws_size,
                              hipStream_t stream) {
    const float* x  = (const float*)d_in[0];
    const float* u1 = (const float*)d_in[1];
    const float* u2 = (const float*)d_in[2];
    const float* W  = (const float*)d_in[3];
    const float* b  = (const float*)d_in[4];
    float* out = (float*)d_out;

    const int N = in_sizes[4];            // 1024
    const int K = in_sizes[3] / N;        // 1024
    const int M = in_sizes[0] / K;        // 16384

    unsigned short* xh = (unsigned short*)d_ws;
    unsigned short* xl = xh + (size_t)M * K;
    unsigned short* wh = xl + (size_t)M * K;
    unsigned short* wl = wh + (size_t)N * K;

    split_fp32_bf16<<<2048, 256, 0, stream>>>(x, xh, xl, (M * K) / 4);
    split_fp32_bf16<<<512, 256, 0, stream>>>(W, wh, wl, (N * K) / 4);

    dim3 grid((M / BM) * (N / BN));
    gumbel_gemm<<<grid, 256, 0, stream>>>(xh, xl, wh, wl, b, u1, u2, out, M, N, K);
}

// Round 2
// 373.042 us; speedup vs baseline: 1.1653x; 1.1653x over previous
//
#include <hip/hip_runtime.h>
#include <hip/hip_bf16.h>

#define BM 128
#define BN 64
#define BK 32

typedef __attribute__((ext_vector_type(8))) short short8;   // 8 bf16 = 4 VGPRs
typedef __attribute__((ext_vector_type(4))) float floatx4;  // MFMA 16x16 C/D

// ---------- bf16 split helpers (RN-even) ----------
__device__ inline unsigned short f2bf(float f) {
    unsigned u = __float_as_uint(f);
    unsigned r = (u + 0x7fffu + ((u >> 16) & 1u)) >> 16;
    return (unsigned short)r;
}
__device__ inline float bf2f(unsigned short s) {
    return __uint_as_float(((unsigned)s) << 16);
}

// ---------- prepass: fp32 -> (hi, lo) bf16 arrays ----------
__global__ __launch_bounds__(256) void split_fp32_bf16(
        const float* __restrict__ src,
        unsigned short* __restrict__ hi, unsigned short* __restrict__ lo, int n4) {
    int i = blockIdx.x * blockDim.x + threadIdx.x;
    int stride = gridDim.x * blockDim.x;
    const float4* s4 = (const float4*)src;
    ushort4* h4 = (ushort4*)hi;
    ushort4* l4 = (ushort4*)lo;
    for (; i < n4; i += stride) {
        float4 v = s4[i];
        ushort4 hv, lv;
        hv.x = f2bf(v.x); lv.x = f2bf(v.x - bf2f(hv.x));
        hv.y = f2bf(v.y); lv.y = f2bf(v.y - bf2f(hv.y));
        hv.z = f2bf(v.z); lv.z = f2bf(v.z - bf2f(hv.z));
        hv.w = f2bf(v.w); lv.w = f2bf(v.w - bf2f(hv.w));
        h4[i] = hv;
        l4[i] = lv;
    }
}

// ---------- fused bf16x3 GEMM + gumbel-sigmoid epilogue ----------
#define AS1U(p) ((const __attribute__((address_space(1))) unsigned int*)(p))
#define AS3U(p) ((__attribute__((address_space(3))) unsigned int*)(p))

__device__ inline int swz(int row) {  // 16B-chunk swizzle; 2-way LDS aliasing is free
    return (row & 3) ^ ((row >> 2) & 1);
}

__global__ __launch_bounds__(256, 4) void gumbel_gemm(
        const unsigned short* __restrict__ xh, const unsigned short* __restrict__ xl,
        const unsigned short* __restrict__ wh, const unsigned short* __restrict__ wl,
        const float* __restrict__ bias, const float* __restrict__ u1,
        const float* __restrict__ u2, float* __restrict__ out,
        int M, int N, int K) {
    __shared__ short As_h[BM * BK];   // 8 KB
    __shared__ short As_l[BM * BK];   // 8 KB
    __shared__ short Bs_h[BN * BK];   // 4 KB
    __shared__ short Bs_l[BN * BK];   // 4 KB

    const int tid  = threadIdx.x;
    const int lane = tid & 63;
    const int wave = tid >> 6;

    // bid = by + 128*bx  =>  bid%8 == by%8: all 16 readers of an A row-panel
    // land on the same XCD (assuming XCD = bid%8 round-robin) -> A stays in L2.
    const int bid = blockIdx.x;
    const int by  = bid & (M / BM - 1);   // M/BM = 128 (pow2)
    const int bx  = bid >> 7;
    const int bm = by * BM;
    const int bn = bx * BN;

    // --- A staging: 512 16B chunks; wave w owns slots [w*128, w*128+128) ---
    int slot0 = wave * 128 + lane;
    int slot1 = slot0 + 64;
    int arow0 = slot0 >> 2, arow1 = slot1 >> 2;
    int gcc0 = (slot0 & 3) ^ swz(arow0);
    int gcc1 = (slot1 & 3) ^ swz(arow1);
    int aoff0 = (bm + arow0) * K + gcc0 * 8;
    int aoff1 = (bm + arow1) * K + gcc1 * 8;
    int ls0 = slot0 * 8;
    int ls1 = slot1 * 8;

    // --- B staging: 256 16B chunks; thread t owns slot t ---
    int bslot = tid;
    int brow = bslot >> 2;
    int gccb = (bslot & 3) ^ swz(brow);
    int boff = (bn + brow) * K + gccb * 8;
    int lsb = bslot * 8;

    // --- fragment addressing (16x16x32: A[m=lane&15][k=(lane>>4)*8+j]) ---
    const int r16  = lane & 15;
    const int quad = lane >> 4;
    const int wm = (wave & 1) * 64;   // 2x2 wave grid, wave tile 64x32
    const int wn = (wave >> 1) * 32;

    floatx4 acc[4][2] = {};

    int aro[4], bro[2];
#pragma unroll
    for (int i = 0; i < 4; i++) {
        int rowa = wm + i * 16 + r16;
        aro[i] = rowa * BK + (quad ^ swz(rowa)) * 8;
    }
#pragma unroll
    for (int j = 0; j < 2; j++) {
        int rowb = wn + j * 16 + r16;
        bro[j] = rowb * BK + (quad ^ swz(rowb)) * 8;
    }

    for (int kb = 0; kb < K; kb += BK) {
        __builtin_amdgcn_global_load_lds(AS1U(xh + aoff0 + kb), AS3U(As_h + ls0), 16, 0, 0);
        __builtin_amdgcn_global_load_lds(AS1U(xh + aoff1 + kb), AS3U(As_h + ls1), 16, 0, 0);
        __builtin_amdgcn_global_load_lds(AS1U(xl + aoff0 + kb), AS3U(As_l + ls0), 16, 0, 0);
        __builtin_amdgcn_global_load_lds(AS1U(xl + aoff1 + kb), AS3U(As_l + ls1), 16, 0, 0);
        __builtin_amdgcn_global_load_lds(AS1U(wh + boff + kb), AS3U(Bs_h + lsb), 16, 0, 0);
        __builtin_amdgcn_global_load_lds(AS1U(wl + boff + kb), AS3U(Bs_l + lsb), 16, 0, 0);
        __syncthreads();

        short8 ah[4], al[4], bh[2], bl[2];
#pragma unroll
        for (int j = 0; j < 2; j++) {
            bh[j] = *(const short8*)(Bs_h + bro[j]);
            bl[j] = *(const short8*)(Bs_l + bro[j]);
        }
#pragma unroll
        for (int i = 0; i < 4; i++) {
            ah[i] = *(const short8*)(As_h + aro[i]);
            al[i] = *(const short8*)(As_l + aro[i]);
        }
#pragma unroll
        for (int i = 0; i < 4; i++) {
#pragma unroll
            for (int j = 0; j < 2; j++) {
                acc[i][j] = __builtin_amdgcn_mfma_f32_16x16x32_bf16(ah[i], bh[j], acc[i][j], 0, 0, 0);
                acc[i][j] = __builtin_amdgcn_mfma_f32_16x16x32_bf16(ah[i], bl[j], acc[i][j], 0, 0, 0);
                acc[i][j] = __builtin_amdgcn_mfma_f32_16x16x32_bf16(al[i], bh[j], acc[i][j], 0, 0, 0);
            }
        }
        __syncthreads();
    }

    // --- epilogue: C/D layout col=lane&15, row=quad*4+reg ---
    const float inv_t = 10.0f;  // 1/TEMP
#pragma unroll
    for (int j = 0; j < 2; j++) {
        int gn = bn + wn + j * 16 + r16;
        float bv = bias[gn];
#pragma unroll
        for (int i = 0; i < 4; i++) {
            int gm0 = bm + wm + i * 16 + quad * 4;
#pragma unroll
            for (int r = 0; r < 4; r++) {
                int idx = (gm0 + r) * N + gn;
                float l = acc[i][j][r] + bv;
                float v1 = __builtin_nontemporal_load(&u1[idx]);
                float v2 = __builtin_nontemporal_load(&u2[idx]);
                float a1 = -__logf(v1);
                float a2 = -__logf(v2);
                float z = (l + __logf(a2 / a1)) * inv_t;
                float o = 1.0f / (1.0f + __expf(-z));
                __builtin_nontemporal_store(o, &out[idx]);
            }
        }
    }
}

extern "C" void kernel_launch(void* const* d_in, const int* in_sizes, int n_in,
                              void* d_out, int out_size, void* d_ws, size_t ws_size,
                              hipStream_t stream) {
    const float* x  = (const float*)d_in[0];
    const float* u1 = (const float*)d_in[1];
    const float* u2 = (const float*)d_in[2];
    const float* W  = (const float*)d_in[3];
    const float* b  = (const float*)d_in[4];
    float* out = (float*)d_out;

    const int N = in_sizes[4];            // 1024
    const int K = in_sizes[3] / N;        // 1024
    const int M = in_sizes[0] / K;        // 16384

    unsigned short* xh = (unsigned short*)d_ws;
    unsigned short* xl = xh + (size_t)M * K;
    unsigned short* wh = xl + (size_t)M * K;
    unsigned short* wl = wh + (size_t)N * K;

    split_fp32_bf16<<<4096, 256, 0, stream>>>(x, xh, xl, (M * K) / 4);
    split_fp32_bf16<<<1024, 256, 0, stream>>>(W, wh, wl, (N * K) / 4);

    dim3 grid((M / BM) * (N / BN));   // 128 * 16 = 2048
    gumbel_gemm<<<grid, 256, 0, stream>>>(xh, xl, wh, wl, b, u1, u2, out, M, N, K);
}

// Round 3
// 336.222 us; speedup vs baseline: 1.2929x; 1.1095x over previous
//
#include <hip/hip_runtime.h>
#include <hip/hip_bf16.h>

#define BM 128
#define BN 128
#define BK 32

typedef __attribute__((ext_vector_type(8))) _Float16 half8;  // 8 fp16 = 4 VGPRs
typedef __attribute__((ext_vector_type(4))) float floatx4;   // MFMA 16x16 C/D

// ---------- prepass: fp32 -> fp16 (RN) ----------
__global__ __launch_bounds__(256) void cvt_fp32_fp16(
        const float* __restrict__ src, _Float16* __restrict__ dst, int n8) {
    int i = blockIdx.x * blockDim.x + threadIdx.x;
    int stride = gridDim.x * blockDim.x;
    const float4* s4 = (const float4*)src;
    half8* d8 = (half8*)dst;
    for (; i < n8; i += stride) {
        float4 a = s4[2 * i];
        float4 b = s4[2 * i + 1];
        half8 h;
        h[0] = (_Float16)a.x; h[1] = (_Float16)a.y;
        h[2] = (_Float16)a.z; h[3] = (_Float16)a.w;
        h[4] = (_Float16)b.x; h[5] = (_Float16)b.y;
        h[6] = (_Float16)b.z; h[7] = (_Float16)b.w;
        d8[i] = h;
    }
}

// ---------- fused fp16 GEMM + gumbel-sigmoid epilogue ----------
// C[m][n] = sum_k x[m][k]*W[n][k];  out = sigmoid((C + b + g1 - g2)/0.1)
#define AS1U(p) ((const __attribute__((address_space(1))) unsigned int*)(p))
#define AS3U(p) ((__attribute__((address_space(3))) unsigned int*)(p))

__device__ inline int swz(int row) {  // 16B-chunk swizzle; 2-way LDS aliasing is free
    return (row & 3) ^ ((row >> 2) & 1);
}

__global__ __launch_bounds__(256) void gumbel_gemm(
        const _Float16* __restrict__ xh, const _Float16* __restrict__ wh,
        const float* __restrict__ bias, const float* __restrict__ u1,
        const float* __restrict__ u2, float* __restrict__ out,
        int M, int N, int K) {
    __shared__ _Float16 As[BM * BK];   // 8 KB
    __shared__ _Float16 Bs[BN * BK];   // 8 KB

    const int tid  = threadIdx.x;
    const int lane = tid & 63;
    const int wave = tid >> 6;

    // bid%8 == by%8 for all 8 sharers of an A row-panel -> same XCD L2.
    const int bid = blockIdx.x;
    const int by  = bid & (M / BM - 1);   // M/BM = 128 (pow2)
    const int bx  = bid >> 7;
    const int bm = by * BM;
    const int bn = bx * BN;

    // --- staging: each tile = 512 16B chunks; thread t owns slots {t, t+256} ---
    // slot s: row = s>>2, global chunk-col = (s&3)^swz(row); LDS chunk = s (swizzle
    // is applied on the GLOBAL side so the wave-uniform-base+lane*16 rule holds).
    int slot0 = wave * 64 + lane;
    int slot1 = slot0 + 256;
    int row0 = slot0 >> 2, row1 = slot1 >> 2;
    int gc0 = (slot0 & 3) ^ swz(row0);
    int gc1 = (slot1 & 3) ^ swz(row1);
    int aoff0 = (bm + row0) * K + gc0 * 8;   // element offsets
    int aoff1 = (bm + row1) * K + gc1 * 8;
    int boff0 = (bn + row0) * K + gc0 * 8;
    int boff1 = (bn + row1) * K + gc1 * 8;
    int ls0 = slot0 * 8;                     // LDS element offset of 16B slot
    int ls1 = slot1 * 8;

    // --- fragment addressing (16x16x32: A[m=lane&15][k=(lane>>4)*8+j]) ---
    const int r16  = lane & 15;
    const int quad = lane >> 4;
    const int wm = (wave & 1) * 64;   // 2x2 wave grid, wave tile 64x64
    const int wn = (wave >> 1) * 64;

    floatx4 acc[4][4] = {};

    int aro[4], bro[4];
#pragma unroll
    for (int i = 0; i < 4; i++) {
        int rowa = wm + i * 16 + r16;
        aro[i] = rowa * BK + (quad ^ swz(rowa)) * 8;
        int rowb = wn + i * 16 + r16;
        bro[i] = rowb * BK + (quad ^ swz(rowb)) * 8;
    }

    for (int kb = 0; kb < K; kb += BK) {
        __builtin_amdgcn_global_load_lds(AS1U(xh + aoff0 + kb), AS3U(As + ls0), 16, 0, 0);
        __builtin_amdgcn_global_load_lds(AS1U(xh + aoff1 + kb), AS3U(As + ls1), 16, 0, 0);
        __builtin_amdgcn_global_load_lds(AS1U(wh + boff0 + kb), AS3U(Bs + ls0), 16, 0, 0);
        __builtin_amdgcn_global_load_lds(AS1U(wh + boff1 + kb), AS3U(Bs + ls1), 16, 0, 0);
        __syncthreads();

        half8 af[4], bf[4];
#pragma unroll
        for (int i = 0; i < 4; i++) {
            af[i] = *(const half8*)(As + aro[i]);
            bf[i] = *(const half8*)(Bs + bro[i]);
        }
#pragma unroll
        for (int i = 0; i < 4; i++) {
#pragma unroll
            for (int j = 0; j < 4; j++) {
                acc[i][j] = __builtin_amdgcn_mfma_f32_16x16x32_f16(af[i], bf[j], acc[i][j], 0, 0, 0);
            }
        }
        __syncthreads();
    }

    // --- epilogue: C/D layout col=lane&15, row=quad*4+reg ---
    const float inv_t = 10.0f;  // 1/TEMP
#pragma unroll
    for (int j = 0; j < 4; j++) {
        int gn = bn + wn + j * 16 + r16;
        float bv = bias[gn];
#pragma unroll
        for (int i = 0; i < 4; i++) {
            int gm0 = bm + wm + i * 16 + quad * 4;
#pragma unroll
            for (int r = 0; r < 4; r++) {
                int idx = (gm0 + r) * N + gn;
                float l = acc[i][j][r] + bv;
                float v1 = __builtin_nontemporal_load(&u1[idx]);
                float v2 = __builtin_nontemporal_load(&u2[idx]);
                float a1 = -__logf(v1);
                float a2 = -__logf(v2);
                float z = (l + __logf(a2 / a1)) * inv_t;
                float o = 1.0f / (1.0f + __expf(-z));
                __builtin_nontemporal_store(o, &out[idx]);
            }
        }
    }
}

extern "C" void kernel_launch(void* const* d_in, const int* in_sizes, int n_in,
                              void* d_out, int out_size, void* d_ws, size_t ws_size,
                              hipStream_t stream) {
    const float* x  = (const float*)d_in[0];
    const float* u1 = (const float*)d_in[1];
    const float* u2 = (const float*)d_in[2];
    const float* W  = (const float*)d_in[3];
    const float* b  = (const float*)d_in[4];
    float* out = (float*)d_out;

    const int N = in_sizes[4];            // 1024
    const int K = in_sizes[3] / N;        // 1024
    const int M = in_sizes[0] / K;        // 16384

    _Float16* xh = (_Float16*)d_ws;
    _Float16* wh = xh + (size_t)M * K;

    cvt_fp32_fp16<<<2048, 256, 0, stream>>>(x, xh, (M * K) / 8);
    cvt_fp32_fp16<<<512, 256, 0, stream>>>(W, wh, (N * K) / 8);

    dim3 grid((M / BM) * (N / BN));   // 128 * 8 = 1024
    gumbel_gemm<<<grid, 256, 0, stream>>>(xh, wh, b, u1, u2, out, M, N, K);
}

// Round 6
// 265.084 us; speedup vs baseline: 1.6398x; 1.2684x over previous
//
#include <hip/hip_runtime.h>
#include <hip/hip_bf16.h>

#define BM 128
#define BN 128
#define BK 32

typedef __attribute__((ext_vector_type(8))) _Float16 half8;  // MFMA A/B frag
typedef __attribute__((ext_vector_type(2))) __fp16 h2raw;    // cvt_pkrtz result
typedef __attribute__((ext_vector_type(4))) float floatx4;   // MFMA C/D frag
typedef __attribute__((ext_vector_type(4))) float f4;        // raw float4

#define AS1U(p) ((const __attribute__((address_space(1))) unsigned int*)(p))
#define AS3U(p) ((__attribute__((address_space(3))) unsigned int*)(p))

union H8 {
    h2raw h2[4];
    half8 h8;
};

__device__ inline half8 cvt8(f4 a, f4 b) {
    H8 u;
    u.h2[0] = __builtin_amdgcn_cvt_pkrtz(a.x, a.y);
    u.h2[1] = __builtin_amdgcn_cvt_pkrtz(a.z, a.w);
    u.h2[2] = __builtin_amdgcn_cvt_pkrtz(b.x, b.y);
    u.h2[3] = __builtin_amdgcn_cvt_pkrtz(b.z, b.w);
    return u.h8;
}

// Single fused kernel: fp32 x,W staged direct-to-LDS; in-register fp16 cvt;
// 16x16x32 f16 MFMA; LDS-transposed float4 gumbel-sigmoid epilogue.
__global__ __launch_bounds__(256, 4) void gumbel_fused(
        const float* __restrict__ x, const float* __restrict__ W,
        const float* __restrict__ bias, const float* __restrict__ u1,
        const float* __restrict__ u2, float* __restrict__ out,
        int M, int N, int K) {
    // 32 KB: K-loop = A fp32 tile (4096 f) + B fp32 tile (4096 f);
    // epilogue reuses as per-wave transpose buffers (4 x 1280 f).
    __shared__ float Smem[8192];
    float* As = Smem;
    float* Bs = Smem + 4096;

    const int tid  = threadIdx.x;
    const int lane = tid & 63;
    const int wave = tid >> 6;

    // bid%8 == by%8 for all 8 sharers of an x row-panel -> same XCD L2.
    const int bid = blockIdx.x;
    const int by  = bid & (M / BM - 1);   // M/BM = 128 (pow2)
    const int bx  = bid >> 7;
    const int bm = by * BM;
    const int bn = bx * BN;

    // --- staging: tile = 1024 16B chunks (8 chunks/row of 32 floats).
    // LDS chunk s <- global (row r = s>>3, chunk col cc = (s&7) ^ (r&7)).
    // Swizzle applied on the GLOBAL side: LDS side stays lane-ordered
    // (global_load_lds rule: lds = wave-uniform base + lane*16).
    int aoff[4], boff[4], lsoff[4];
#pragma unroll
    for (int rep = 0; rep < 4; rep++) {
        int s = wave * 64 + lane + rep * 256;
        int r = s >> 3;
        int cc = (s & 7) ^ (r & 7);
        aoff[rep] = (bm + r) * K + cc * 4;
        boff[rep] = (bn + r) * K + cc * 4;
        lsoff[rep] = s * 4;  // float offset (== r*32 + (s&7)*4)
    }

    // --- fragment addressing (16x16x32: A[m=lane&15][k=(lane>>4)*8+j]) ---
    const int r16  = lane & 15;
    const int quad = lane >> 4;
    const int wm = (wave & 1) * 64;   // 2x2 wave grid, wave tile 64x64
    const int wn = (wave >> 1) * 64;

    floatx4 acc[4][4] = {};

    // LDS position of global k-chunk 2*quad for row ra is (2*quad)^(ra&7);
    // position of chunk 2*quad+1 is that ^1.  (XOR involution: position p
    // holds global chunk p^(r&7), so p0 ALWAYS holds the even/lower chunk.)
    int aro[4], bro[4];
#pragma unroll
    for (int i = 0; i < 4; i++) {
        int ra = wm + i * 16 + r16;
        aro[i] = ra * 32 + ((2 * quad) ^ (ra & 7)) * 4;
        int rb = wn + i * 16 + r16;
        bro[i] = rb * 32 + ((2 * quad) ^ (rb & 7)) * 4;
    }

    for (int kb = 0; kb < K; kb += BK) {
#pragma unroll
        for (int rep = 0; rep < 4; rep++) {
            __builtin_amdgcn_global_load_lds(AS1U(x + aoff[rep] + kb), AS3U(As + lsoff[rep]), 16, 0, 0);
            __builtin_amdgcn_global_load_lds(AS1U(W + boff[rep] + kb), AS3U(Bs + lsoff[rep]), 16, 0, 0);
        }
        __syncthreads();

        half8 af[4], bf[4];
#pragma unroll
        for (int i = 0; i < 4; i++) {
            // partner chunk position = p0 ^ 1 -> float offset low-5-bits ^ 4
            f4 a0 = *(const f4*)(As + aro[i]);
            f4 a1 = *(const f4*)(As + ((aro[i] & ~31) | ((aro[i] & 31) ^ 4)));
            af[i] = cvt8(a0, a1);   // a0 = k-chunk 2*quad, a1 = 2*quad+1, always
            f4 b0 = *(const f4*)(Bs + bro[i]);
            f4 b1 = *(const f4*)(Bs + ((bro[i] & ~31) | ((bro[i] & 31) ^ 4)));
            bf[i] = cvt8(b0, b1);
        }
#pragma unroll
        for (int i = 0; i < 4; i++) {
#pragma unroll
            for (int j = 0; j < 4; j++) {
                acc[i][j] = __builtin_amdgcn_mfma_f32_16x16x32_f16(af[i], bf[j], acc[i][j], 0, 0, 0);
            }
        }
        __syncthreads();
    }

    // --- epilogue: transpose each 16x64 acc row-group through LDS, then
    // fully-coalesced float4 u1/u2/out accesses. ---
    // Per-wave region: T[col][row], col in [0,64), row stride 20.
    // __syncthreads (not waitcnt) so the COMPILER cannot reorder the
    // cross-lane LDS write->read (it can't see lane-to-lane deps).
    float* T = Smem + wave * 1280;
    const float inv_t = 10.0f;  // 1/TEMP

#pragma unroll
    for (int i = 0; i < 4; i++) {
        // acc[i][j][r] = C[row = quad*4+r][col = j*16+r16] of this 16x64 group
#pragma unroll
        for (int j = 0; j < 4; j++) {
            int col = j * 16 + r16;
            f4 v = {acc[i][j][0], acc[i][j][1], acc[i][j][2], acc[i][j][3]};
            *(f4*)(T + col * 20 + quad * 4) = v;
        }
        __syncthreads();

#pragma unroll
        for (int rep = 0; rep < 2; rep++) {
#pragma unroll
            for (int rep2 = 0; rep2 < 2; rep2++) {
                int rr = (lane >> 3) + rep * 8;        // row in [0,16)
                int ch = (lane & 7) + rep2 * 8;        // float4 chunk in [0,16)
                int gm = bm + wm + i * 16 + rr;
                int gc = bn + wn + ch * 4;
                f4 l4;
                l4.x = T[(ch * 4 + 0) * 20 + rr];
                l4.y = T[(ch * 4 + 1) * 20 + rr];
                l4.z = T[(ch * 4 + 2) * 20 + rr];
                l4.w = T[(ch * 4 + 3) * 20 + rr];
                f4 bv = *(const f4*)(bias + gc);
                int idx = gm * N + gc;
                f4 v1 = __builtin_nontemporal_load((const f4*)(u1 + idx));
                f4 v2 = __builtin_nontemporal_load((const f4*)(u2 + idx));
                f4 o;
                {
                    float z = (l4.x + bv.x + __logf(__logf(v2.x) / __logf(v1.x))) * inv_t;
                    o.x = 1.0f / (1.0f + __expf(-z));
                }
                {
                    float z = (l4.y + bv.y + __logf(__logf(v2.y) / __logf(v1.y))) * inv_t;
                    o.y = 1.0f / (1.0f + __expf(-z));
                }
                {
                    float z = (l4.z + bv.z + __logf(__logf(v2.z) / __logf(v1.z))) * inv_t;
                    o.z = 1.0f / (1.0f + __expf(-z));
                }
                {
                    float z = (l4.w + bv.w + __logf(__logf(v2.w) / __logf(v1.w))) * inv_t;
                    o.w = 1.0f / (1.0f + __expf(-z));
                }
                __builtin_nontemporal_store(o, (f4*)(out + idx));
            }
        }
        __syncthreads();   // all reads of T done before next i overwrites it
    }
}

extern "C" void kernel_launch(void* const* d_in, const int* in_sizes, int n_in,
                              void* d_out, int out_size, void* d_ws, size_t ws_size,
                              hipStream_t stream) {
    const float* x  = (const float*)d_in[0];
    const float* u1 = (const float*)d_in[1];
    const float* u2 = (const float*)d_in[2];
    const float* W  = (const float*)d_in[3];
    const float* b  = (const float*)d_in[4];
    float* out = (float*)d_out;

    const int N = in_sizes[4];            // 1024
    const int K = in_sizes[3] / N;        // 1024
    const int M = in_sizes[0] / K;        // 16384

    dim3 grid((M / BM) * (N / BN));       // 128 * 8 = 1024
    gumbel_fused<<<grid, 256, 0, stream>>>(x, W, b, u1, u2, out, M, N, K);
}